// Round 3
// baseline (97.889 us; speedup 1.0000x reference)
//
#include <hip/hip_runtime.h>
#include <hip/hip_bf16.h>

#define NN 8192
#define FIN 256
#define FOUT 128
#define KSPLIT 2
#define KHALF (NN / KSPLIT)

typedef __attribute__((ext_vector_type(8))) short short8;
typedef __attribute__((ext_vector_type(4))) float f32x4;
typedef unsigned short u16;

__device__ inline u16 bf16r(float v) {
  return __builtin_bit_cast(u16, __float2bfloat16(v));
}

// ---- fused: h = x@W (regs), e = leaky_relu(h@a), w = exp(e), gT = bf16(w*h)^T ----
__global__ __launch_bounds__(256) void k_prep(const float* __restrict__ x,
                                              const float* __restrict__ W,
                                              const float* __restrict__ a,
                                              float* __restrict__ wexp,
                                              u16* __restrict__ gT) {
  __shared__ float xs[32 * 256];
  __shared__ float ap[4][16];
  __shared__ float wsh[32];
  __shared__ u16 gsh[32][132];
  const int t = threadIdx.x;
  const int r0 = blockIdx.x * 32;

  const float4* xg = (const float4*)(x + (size_t)r0 * FIN);
  float4* xs4 = (float4*)xs;
#pragma unroll
  for (int p = 0; p < 8; ++p) xs4[p * 256 + t] = xg[p * 256 + t];
  __syncthreads();

  const int f = t & 127;
  const int half = t >> 7;
  float acc[16];
#pragma unroll
  for (int i = 0; i < 16; ++i) acc[i] = 0.f;

  const float4* xsr = (const float4*)(xs + half * 16 * 256);
  for (int k4 = 0; k4 < 64; ++k4) {
    float w0 = W[(k4 * 4 + 0) * FOUT + f];
    float w1 = W[(k4 * 4 + 1) * FOUT + f];
    float w2 = W[(k4 * 4 + 2) * FOUT + f];
    float w3 = W[(k4 * 4 + 3) * FOUT + f];
#pragma unroll
    for (int i = 0; i < 16; ++i) {
      float4 xv = xsr[i * 64 + k4];
      acc[i] = fmaf(xv.x, w0, acc[i]);
      acc[i] = fmaf(xv.y, w1, acc[i]);
      acc[i] = fmaf(xv.z, w2, acc[i]);
      acc[i] = fmaf(xv.w, w3, acc[i]);
    }
  }

  const float af = a[f];
  float part[16];
#pragma unroll
  for (int i = 0; i < 16; ++i) part[i] = acc[i] * af;
#pragma unroll
  for (int i = 0; i < 16; ++i) {
#pragma unroll
    for (int off = 32; off >= 1; off >>= 1) part[i] += __shfl_xor(part[i], off);
  }
  const int wvid = t >> 6;
  if ((t & 63) == 0) {
#pragma unroll
    for (int i = 0; i < 16; ++i) ap[wvid][i] = part[i];
  }
  __syncthreads();
  if (t < 32) {
    int i = t & 15, hh = t >> 4;
    float alpha = ap[hh * 2][i] + ap[hh * 2 + 1][i];
    float ee = alpha > 0.f ? alpha : 0.2f * alpha;
    float wv = __expf(fminf(ee, 80.f));  // softmax shift-invariance: no global max needed
    wsh[t] = wv;
    wexp[r0 + t] = wv;
  }
  __syncthreads();

#pragma unroll
  for (int i = 0; i < 16; ++i) {
    int row = half * 16 + i;
    gsh[row][f] = bf16r(acc[i] * wsh[row]);
  }
  __syncthreads();

  const int ff = t >> 1;
  const int jc = (t & 1) * 16;
  u16* dst = gT + (size_t)ff * NN + r0 + jc;
#pragma unroll
  for (int q = 0; q < 4; ++q) {
    ushort4 v;
    v.x = gsh[jc + q * 4 + 0][ff];
    v.y = gsh[jc + q * 4 + 1][ff];
    v.z = gsh[jc + q * 4 + 2][ff];
    v.w = gsh[jc + q * 4 + 3][ff];
    *(ushort4*)(dst + q * 4) = v;
  }
}

// ---- partial: numer[ks] = adj[:, ksrange] @ g[ksrange], denom[ks] = adj @ w ----
// 4-deep register prefetch, raw s_barrier (no vmcnt drain), counted lgkmcnt only.
__global__ __launch_bounds__(512, 4) void k_gemm(const int* __restrict__ adj,
                                                 const u16* __restrict__ gT,
                                                 const float* __restrict__ w,
                                                 float* __restrict__ numer,
                                                 float* __restrict__ denom) {
  __shared__ u16 Ash[2][32 * 64];    // [row][k], XOR-swizzled
  __shared__ u16 Bsh[2][128 * 64];   // [f][k],   XOR-swizzled
  __shared__ float denom_sh[32];

  const int t = threadIdx.x;
  const int lane = t & 63;
  const int wvid = t >> 6;
  const int wr = wvid >> 2;
  const int wc = wvid & 3;
  const int r0 = blockIdx.x * 32;
  const int ks = blockIdx.y;
  const size_t kbase = (size_t)ks * KHALF;

  const int ar = t >> 4;
  const int ako = (t & 15) * 4;
  const int* adjrow = adj + (size_t)(r0 + ar) * NN + kbase + ako;
  const float* wp = w + kbase + ako;
  const int bfr = t >> 3;
  const int bck = (t & 7) * 8;
  const u16* gTb = gT + kbase + (size_t)bfr * NN + bck;

  struct Set {
    int4 av;
    float4 wq;
    short8 bb0, bb1;
  };
  Set s0, s1, s2, s3;
  f32x4 acc0 = {0.f, 0.f, 0.f, 0.f};
  f32x4 acc1 = {0.f, 0.f, 0.f, 0.f};
  float dpart = 0.f;

  const int abyte = ar * 128 + ((ako * 2) ^ ((ar & 7) << 4));
  const int bbyte = bfr * 128 + ((bck * 2) ^ ((bfr & 7) << 4));
  const int swz = (lane & 7) << 4;
  const int arow = wr * 16 + (lane & 15);
  const int bcol = wc * 32 + (lane & 15);
  const int k0 = (lane >> 4) * 16;

  auto LOAD = [&](Set& S, int T) {
    S.av = *(const int4*)(adjrow + T * 64);
    S.wq = *(const float4*)(wp + T * 64);
    S.bb0 = *(const short8*)(gTb + T * 64);
    S.bb1 = *(const short8*)(gTb + T * 64 + (size_t)64 * NN);
  };
  auto STORE = [&](Set& S, int buf) {
    dpart += (S.av.x ? S.wq.x : 0.f) + (S.av.y ? S.wq.y : 0.f) +
             (S.av.z ? S.wq.z : 0.f) + (S.av.w ? S.wq.w : 0.f);
    ushort4 a4;
    a4.x = S.av.x ? (u16)0x3F80 : (u16)0;
    a4.y = S.av.y ? (u16)0x3F80 : (u16)0;
    a4.z = S.av.z ? (u16)0x3F80 : (u16)0;
    a4.w = S.av.w ? (u16)0x3F80 : (u16)0;
    *(ushort4*)((char*)&Ash[buf][0] + abyte) = a4;
    *(short8*)((char*)&Bsh[buf][0] + bbyte) = S.bb0;
    *(short8*)((char*)&Bsh[buf][0] + bbyte + 64 * 128) = S.bb1;
  };

  short8 fa0, fb00, fb10, fa1, fb01, fb11;
  auto READS = [&](int buf) {
    const char* A = (const char*)&Ash[buf][0];
    const char* B = (const char*)&Bsh[buf][0];
    fa0 = *(const short8*)(A + arow * 128 + (k0 ^ swz));
    fb00 = *(const short8*)(B + bcol * 128 + (k0 ^ swz));
    fb10 = *(const short8*)(B + (bcol + 16) * 128 + (k0 ^ swz));
    fa1 = *(const short8*)(A + arow * 128 + ((64 + k0) ^ swz));
    fb01 = *(const short8*)(B + bcol * 128 + ((64 + k0) ^ swz));
    fb11 = *(const short8*)(B + (bcol + 16) * 128 + ((64 + k0) ^ swz));
  };
  auto MFMAS = [&]() {
    acc0 = __builtin_amdgcn_mfma_f32_16x16x32_bf16(fa0, fb00, acc0, 0, 0, 0);
    acc1 = __builtin_amdgcn_mfma_f32_16x16x32_bf16(fa0, fb10, acc1, 0, 0, 0);
    acc0 = __builtin_amdgcn_mfma_f32_16x16x32_bf16(fa1, fb01, acc0, 0, 0, 0);
    acc1 = __builtin_amdgcn_mfma_f32_16x16x32_bf16(fa1, fb11, acc1, 0, 0, 0);
  };

#define BODY(J, SW, DOST, DOLD)                             \
  do {                                                      \
    if (DOST) STORE(SW, ((J) + 1) & 1);                     \
    if (DOLD) LOAD(SW, (J) + 5);                            \
    READS((J) & 1);                                         \
    asm volatile("s_waitcnt lgkmcnt(0)" ::: "memory");      \
    __builtin_amdgcn_s_barrier();                           \
    __builtin_amdgcn_sched_barrier(0);                      \
    MFMAS();                                                \
  } while (0)

  // prologue: tile 0 -> LDS buf0; tiles 1..4 in flight (16 loads)
  LOAD(s0, 0);
  STORE(s0, 0);
  LOAD(s1, 1);
  LOAD(s2, 2);
  LOAD(s3, 3);
  LOAD(s0, 4);
  asm volatile("s_waitcnt lgkmcnt(0)" ::: "memory");
  __builtin_amdgcn_s_barrier();
  __builtin_amdgcn_sched_barrier(0);

  for (int jb = 0; jb < 56; jb += 4) {
    BODY(jb + 0, s1, 1, 1);
    BODY(jb + 1, s2, 1, 1);
    BODY(jb + 2, s3, 1, 1);
    BODY(jb + 3, s0, 1, 1);
  }
  BODY(56, s1, 1, 1);
  BODY(57, s2, 1, 1);
  BODY(58, s3, 1, 1);
  BODY(59, s0, 1, 0);
  BODY(60, s1, 1, 0);
  BODY(61, s2, 1, 0);
  BODY(62, s3, 1, 0);
  BODY(63, s0, 0, 0);
#undef BODY

  // denominator: reduce the 16 partials per row
  dpart += __shfl_xor(dpart, 1);
  dpart += __shfl_xor(dpart, 2);
  dpart += __shfl_xor(dpart, 4);
  dpart += __shfl_xor(dpart, 8);
  if ((t & 15) == 0) denom_sh[ar] = dpart;
  __syncthreads();

#pragma unroll
  for (int q = 0; q < 4; ++q) {
    int row = wr * 16 + (lane >> 4) * 4 + q;
    int col = wc * 32 + (lane & 15);
    float* np = numer + ((size_t)ks * NN + r0 + row) * FOUT + col;
    np[0] = acc0[q];
    np[16] = acc1[q];
  }
  if (t < 32) denom[(size_t)ks * NN + r0 + t] = denom_sh[t];
}

// ---- out = (n0 + n1) / (d0 + d1) ----
__global__ __launch_bounds__(256) void k_comb(const float* __restrict__ numer,
                                              const float* __restrict__ denom,
                                              float* __restrict__ out) {
  const int idx = blockIdx.x * 256 + threadIdx.x;
  const int row = idx >> 5;
  const int fc = (idx & 31) * 4;
  float4 n0 = *(const float4*)(numer + (size_t)row * FOUT + fc);
  float4 n1 = *(const float4*)(numer + (size_t)(NN + row) * FOUT + fc);
  float d = denom[row] + denom[NN + row];
  float inv = 1.0f / d;
  float4 o;
  o.x = (n0.x + n1.x) * inv;
  o.y = (n0.y + n1.y) * inv;
  o.z = (n0.z + n1.z) * inv;
  o.w = (n0.w + n1.w) * inv;
  *(float4*)(out + (size_t)row * FOUT + fc) = o;
}

extern "C" void kernel_launch(void* const* d_in, const int* in_sizes, int n_in,
                              void* d_out, int out_size, void* d_ws, size_t ws_size,
                              hipStream_t stream) {
  const float* x = (const float*)d_in[0];
  const int* adj = (const int*)d_in[1];
  const float* W = (const float*)d_in[2];
  const float* a = (const float*)d_in[3];
  float* out = (float*)d_out;

  char* ws = (char*)d_ws;
  float* wexp = (float*)ws;                        // 32 KB
  u16* gT = (u16*)(ws + 64 * 1024);                // 2 MB
  float* numer = (float*)(ws + 4 * 1024 * 1024);   // 8 MB (2 x 8192 x 128)
  float* denom = (float*)(ws + 12 * 1024 * 1024);  // 64 KB (2 x 8192)

  hipLaunchKernelGGL(k_prep, dim3(NN / 32), dim3(256), 0, stream, x, W, a, wexp, gT);
  hipLaunchKernelGGL(k_gemm, dim3(NN / 32, KSPLIT), dim3(512), 0, stream, adj, gT, wexp,
                     numer, denom);
  hipLaunchKernelGGL(k_comb, dim3((NN * FOUT / 4) / 256), dim3(256), 0, stream, numer,
                     denom, out);
}